// Round 5
// baseline (161.019 us; speedup 1.0000x reference)
//
#include <hip/hip_runtime.h>

typedef __attribute__((ext_vector_type(8))) _Float16 f16x8;
typedef __attribute__((ext_vector_type(16))) float f32x16;

#define MFMA32(a, b, c) __builtin_amdgcn_mfma_f32_32x32x16_f16((a), (b), (c), 0, 0, 0)

// ---------------- helpers ----------------
__device__ __forceinline__ float tanh_fast(float x) {
  return 1.0f - 2.0f / (__expf(2.0f * x) + 1.0f);
}

// ---------------- K1: quantum sim -> q + per-block stat partials ----------------
// Tail blocks convert weights to fp16 and zero the s2 stat buffers (consumed
// only by K2, which is ordered after K1 by the dispatch boundary).
__global__ __launch_bounds__(256) void k_quantum(
    const float4* __restrict__ x, const float* __restrict__ qp,
    float4* __restrict__ qout, float* __restrict__ s1part, int QB,
    const float* __restrict__ w2, const float* __restrict__ w3,
    _Float16* __restrict__ w2f, _Float16* __restrict__ w3f,
    float* __restrict__ s2sum, float* __restrict__ s2sq)
{
  int tid = threadIdx.x;

  if (blockIdx.x >= QB) {   // weight-conversion tail blocks (256 of them)
    int tb = blockIdx.x - QB;
    int i = tb * 256 + tid;   // 0..65535
    w3f[i] = (_Float16)w3[i];
    if (i < 32768) w2f[i] = (_Float16)w2[i];
    if (tb == 0) { s2sum[tid] = 0.f; s2sq[tid] = 0.f; }
    return;
  }

  size_t r = (size_t)blockIdx.x * 256 + tid;
  float4 xr = x[r];
  float xv[4] = {xr.x, xr.y, xr.z, xr.w};

  float re[16], im[16];
#pragma unroll
  for (int i = 0; i < 16; i++) { re[i] = 0.f; im[i] = 0.f; }
  re[0] = 1.f;

#pragma unroll
  for (int d = 0; d < 3; d++) {
#pragma unroll
    for (int q = 0; q < 4; q++) {
      float th = 0.5f * (xv[q] + qp[d * 8 + q]);
      float s, c; __sincosf(th, &s, &c);
      int m = 8 >> q;
#pragma unroll
      for (int i = 0; i < 16; i++) if (!(i & m)) {
        int i1 = i | m;
        float r0 = re[i], i0 = im[i], r1 = re[i1], i1v = im[i1];
        re[i]  = c * r0 - s * r1;  im[i]  = c * i0 - s * i1v;
        re[i1] = s * r0 + c * r1;  im[i1] = s * i0 + c * i1v;
      }
    }
#pragma unroll
    for (int q = 0; q < 4; q++) {
      int mc = 8 >> q, mt = 8 >> ((q + 1) & 3);
#pragma unroll
      for (int i = 0; i < 16; i++) if ((i & mc) && !(i & mt)) {
        int i1 = i | mt;
        float tr = re[i]; re[i] = re[i1]; re[i1] = tr;
        float ti = im[i]; im[i] = im[i1]; im[i1] = ti;
      }
    }
#pragma unroll
    for (int q = 0; q < 4; q++) {
      float th = 0.5f * qp[d * 8 + 4 + q];
      float s, c; __sincosf(th, &s, &c);
      int m = 8 >> q;
#pragma unroll
      for (int i = 0; i < 16; i++) {
        float pi = (i & m) ? s : -s;
        float r0 = re[i], i0 = im[i];
        re[i] = r0 * c - i0 * pi;
        im[i] = r0 * pi + i0 * c;
      }
    }
  }

  float p[16];
#pragma unroll
  for (int i = 0; i < 16; i++) p[i] = re[i] * re[i] + im[i] * im[i];
  float z[4];
#pragma unroll
  for (int q = 0; q < 4; q++) {
    int m = 8 >> q; float acc = 0.f;
#pragma unroll
    for (int i = 0; i < 16; i++) acc += (i & m) ? -p[i] : p[i];
    z[q] = acc;
  }
  qout[r] = make_float4(z[0], z[1], z[2], z[3]);

  float st[14];
  st[0] = z[0]; st[1] = z[1]; st[2] = z[2]; st[3] = z[3];
  int p5 = 4;
#pragma unroll
  for (int a = 0; a < 4; a++)
#pragma unroll
    for (int b = a; b < 4; b++) st[p5++] = z[a] * z[b];

  __shared__ float part[4][14];
  int lane = tid & 63, wv = tid >> 6;
#pragma unroll
  for (int s = 0; s < 14; s++) {
    float v = st[s];
#pragma unroll
    for (int o = 32; o; o >>= 1) v += __shfl_down(v, o, 64);
    if (lane == 0) part[wv][s] = v;
  }
  __syncthreads();
  if (tid < 14)
    s1part[blockIdx.x * 14 + tid] =
        part[0][tid] + part[1][tid] + part[2][tid] + part[3][tid];
}

// ---------------- K2: reduce stats + fold BN1 (per block) -> stage a1 (exported) ----------------
// 128 rows/block, 512 threads (8 waves x 32-col strips).
// a1 is written to global (bit-exact fp16) so K3 can skip its recomputation.
__global__ __launch_bounds__(512, 4) void k_fc2stats(
    const float4* __restrict__ q, const float* __restrict__ s1part, int QB,
    const float* __restrict__ w1p, const float* __restrict__ b1p,
    const float* __restrict__ g1p, const float* __restrict__ bb1p,
    const _Float16* __restrict__ w2f, const float* __restrict__ b2,
    float* __restrict__ s2sum, float* __restrict__ s2sq,
    _Float16* __restrict__ a1g, float invB)
{
  __shared__ __align__(16) float4 qs[128];                 // 2 KB
  __shared__ __align__(16) _Float16 a1[128 * 136];         // 34.8 KB
  __shared__ float r1[14][32];
  __shared__ float s1v[14];
  __shared__ __align__(16) float4 w1eS[128];
  __shared__ float b1eS[128];

  int t = threadIdx.x;
  int lane = t & 63, w = t >> 6, m32 = lane & 31, hh = lane >> 5;
  size_t rowBase = (size_t)blockIdx.x * 128;

  if (t < 128) qs[t] = q[rowBase + t];
  if (t < 448) {                       // reduce partials, 32-way per stat
    int s = t >> 5, k = t & 31;
    float acc = 0.f;
    for (int j = k; j < QB; j += 32) acc += s1part[j * 14 + s];
    r1[s][k] = acc;
  }
  __syncthreads();
  if (t < 14) {
    float v = 0.f;
#pragma unroll
    for (int k = 0; k < 32; k++) v += r1[t][k];
    s1v[t] = v * invB;
  }
  __syncthreads();

  // fold BN1 into effective fc1 weights (per block, in LDS)
  if (t < 128) {
    int j = t;
    float S0 = s1v[0], S1 = s1v[1], S2 = s1v[2], S3 = s1v[3];
    float M00 = s1v[4], M01 = s1v[5], M02 = s1v[6], M03 = s1v[7];
    float M11 = s1v[8], M12 = s1v[9], M13 = s1v[10];
    float M22 = s1v[11], M23 = s1v[12], M33 = s1v[13];
    float w0 = w1p[j * 4 + 0], wv1 = w1p[j * 4 + 1], wv2 = w1p[j * 4 + 2], wv3 = w1p[j * 4 + 3];
    float b = b1p[j];
    float wq = w0 * S0 + wv1 * S1 + wv2 * S2 + wv3 * S3;
    float mm = wq + b;
    float quad = w0 * w0 * M00 + wv1 * wv1 * M11 + wv2 * wv2 * M22 + wv3 * wv3 * M33
               + 2.f * (w0 * wv1 * M01 + w0 * wv2 * M02 + w0 * wv3 * M03
                      + wv1 * wv2 * M12 + wv1 * wv3 * M13 + wv2 * wv3 * M23);
    float e2 = quad + 2.f * b * wq + b * b;
    float var = e2 - mm * mm;
    float sv = g1p[j] * rsqrtf(var + 1e-5f);
    w1eS[j] = make_float4(sv * w0, sv * wv1, sv * wv2, sv * wv3);
    b1eS[j] = sv * b + bb1p[j] - sv * mm;
  }
  __syncthreads();

  // stage a1 = relu(W1e q + b1e) as fp16 (128 rows x 128 cols, 32 rows/thread)
  {
    int j = t & 127;
    float4 w1v = w1eS[j];
    float b1v = b1eS[j];
    int rb = (t >> 7) * 32;
#pragma unroll 8
    for (int i = 0; i < 32; i++) {
      float4 qv = qs[rb + i];
      float v = fmaf(w1v.x, qv.x, fmaf(w1v.y, qv.y, fmaf(w1v.z, qv.z, fmaf(w1v.w, qv.w, b1v))));
      a1[(rb + i) * 136 + j] = (_Float16)fmaxf(v, 0.f);
    }
  }
  __syncthreads();

  // export a1 tile to global (bit-exact cache for K3): 32 KB/block, 16B vectors
  {
    int row = t >> 2, ch = t & 3;
    const f16x8* src = (const f16x8*)&a1[row * 136 + ch * 32];
    f16x8* dst = (f16x8*)(a1g + (rowBase + row) * 128 + ch * 32);
#pragma unroll
    for (int k = 0; k < 4; k++) dst[k] = src[k];
  }

  // fc2: wave w owns cols [w*32, w*32+32)
  f32x16 acc[4];
#pragma unroll
  for (int mt = 0; mt < 4; mt++)
#pragma unroll
    for (int r = 0; r < 16; r++) acc[mt][r] = 0.f;

  int col = w * 32 + m32;
#pragma unroll
  for (int ks = 0; ks < 8; ks++) {               // K = 128, step 16
    int kb = ks * 16 + hh * 8;
    f16x8 bfr = *(const f16x8*)(w2f + (size_t)col * 128 + kb);
#pragma unroll
    for (int mt = 0; mt < 4; mt++) {
      f16x8 afr = *(const f16x8*)&a1[(mt * 32 + m32) * 136 + kb];
      acc[mt] = MFMA32(afr, bfr, acc[mt]);
    }
  }

  // per-column sum & sumsq of h2 = acc + b2 over the block's 128 rows
  {
    float b2v = b2[col];
    float s = 0.f, ss = 0.f;
#pragma unroll
    for (int mt = 0; mt < 4; mt++)
#pragma unroll
      for (int r = 0; r < 16; r++) {
        float hv = acc[mt][r] + b2v;
        s += hv; ss += hv * hv;
      }
    s += __shfl_down(s, 32, 64);
    ss += __shfl_down(ss, 32, 64);
    if (lane < 32) {
      atomicAdd(&s2sum[col], s);
      atomicAdd(&s2sq[col], ss);
    }
  }
}

// ---------------- K3: BN2 coefs -> fc2 (A from cached a1g) -> BN2+ReLU -> fc3 -> tanh ----------------
// Prologue reduced to the tiny BN2-coef computation; a1 is loaded, not recomputed.
__global__ __launch_bounds__(512, 4) void k_final(
    const _Float16* __restrict__ a1g,
    const _Float16* __restrict__ w2f, const float* __restrict__ b2,
    const float* __restrict__ g2p, const float* __restrict__ bb2p,
    const float* __restrict__ s2sum, const float* __restrict__ s2sq,
    const _Float16* __restrict__ w3f, const float* __restrict__ b3,
    float* __restrict__ out, float invB)
{
  __shared__ __align__(16) _Float16 un[128 * 264];         // 66 KB: a2 staging
  __shared__ float sc2s[256];
  __shared__ float t2s[256];

  int t = threadIdx.x;
  int lane = t & 63, w = t >> 6, m32 = lane & 31, hh = lane >> 5;
  size_t rowBase = (size_t)blockIdx.x * 128;
  const f16x8* a1t = (const f16x8*)(a1g + rowBase * 128);  // this block's a1 tile

  // BN2 affine coefficients (first 256 threads; b2 folded in)
  if (t < 256) {
    float mcol = s2sum[t] * invB;
    float vcol = s2sq[t] * invB - mcol * mcol;
    float sv = g2p[t] * rsqrtf(vcol + 1e-5f);
    sc2s[t] = sv;
    t2s[t] = bb2p[t] - mcol * sv + b2[t] * sv;   // a2 = relu(sv*acc_nobias + t2)
  }
  __syncthreads();

  // ---- fc2: wave w owns cols [w*32, w*32+32); A-fragments straight from a1g ----
  int col = w * 32 + m32;
  f32x16 acc[4];
#pragma unroll
  for (int mt = 0; mt < 4; mt++)
#pragma unroll
    for (int r = 0; r < 16; r++) acc[mt][r] = 0.f;

#pragma unroll
  for (int ks = 0; ks < 8; ks++) {
    int kb = ks * 16 + hh * 8;
    f16x8 bfr = *(const f16x8*)(w2f + (size_t)col * 128 + kb);
#pragma unroll
    for (int mt = 0; mt < 4; mt++) {
      f16x8 afr = a1t[(mt * 32 + m32) * 16 + ks * 2 + hh];
      acc[mt] = MFMA32(afr, bfr, acc[mt]);
    }
  }

  // ---- BN2 + ReLU -> a2 (fp16) ----
  {
    float sv = sc2s[col], tv = t2s[col];
#pragma unroll
    for (int mt = 0; mt < 4; mt++)
#pragma unroll
      for (int r = 0; r < 16; r++) {
        int row = mt * 32 + (r & 3) + 8 * (r >> 2) + 4 * hh;
        un[row * 264 + col] = (_Float16)fmaxf(fmaf(acc[mt][r], sv, tv), 0.f);
      }
  }
  __syncthreads();

  // ---- fc3 (K = 256) ----
  f32x16 acc3[4];
#pragma unroll
  for (int mt = 0; mt < 4; mt++)
#pragma unroll
    for (int r = 0; r < 16; r++) acc3[mt][r] = 0.f;

#pragma unroll
  for (int ks = 0; ks < 16; ks++) {
    int kb = ks * 16 + hh * 8;
    f16x8 bfr = *(const f16x8*)(w3f + (size_t)col * 256 + kb);
#pragma unroll
    for (int mt = 0; mt < 4; mt++) {
      f16x8 afr = *(const f16x8*)&un[(mt * 32 + m32) * 264 + kb];
      acc3[mt] = MFMA32(afr, bfr, acc3[mt]);
    }
  }

  // ---- tanh epilogue ----
  {
    float b3v = b3[col];
#pragma unroll
    for (int mt = 0; mt < 4; mt++)
#pragma unroll
      for (int r = 0; r < 16; r++) {
        int row = mt * 32 + (r & 3) + 8 * (r >> 2) + 4 * hh;
        out[(rowBase + row) * 256 + col] = tanh_fast(acc3[mt][r] + b3v);
      }
  }
}

// ---------------- host launcher ----------------
extern "C" void kernel_launch(void* const* d_in, const int* in_sizes, int n_in,
                              void* d_out, int out_size, void* d_ws, size_t ws_size,
                              hipStream_t stream) {
  const float* x     = (const float*)d_in[0];
  const float* qp    = (const float*)d_in[1];
  const float* fc1_w = (const float*)d_in[2];
  const float* fc1_b = (const float*)d_in[3];
  const float* bn1_g = (const float*)d_in[4];
  const float* bn1_b = (const float*)d_in[5];
  const float* fc2_w = (const float*)d_in[6];
  const float* fc2_b = (const float*)d_in[7];
  const float* bn2_g = (const float*)d_in[8];
  const float* bn2_b = (const float*)d_in[9];
  const float* fc3_w = (const float*)d_in[10];
  const float* fc3_b = (const float*)d_in[11];
  float* out = (float*)d_out;
  float* ws  = (float*)d_ws;

  int B = in_sizes[0] / 4;
  int QB = B / 256;
  float invB = 1.0f / (float)B;

  // ws layout: q[B*4] f32 | s1part[QB*14] | s2sum[256] | s2sq[256] |
  //            w2f[32768] f16 | w3f[65536] f16 | a1g[B*128] f16   (no memset needed)
  float* wq     = ws;
  float* s1part = ws + (size_t)4 * B;
  float* s2sum  = s1part + (size_t)QB * 14;
  float* s2sq   = s2sum + 256;
  _Float16* w2f = (_Float16*)(s2sq + 256);
  _Float16* w3f = w2f + 32768;
  _Float16* a1g = w3f + 65536;

  k_quantum<<<QB + 256, 256, 0, stream>>>((const float4*)x, qp, (float4*)wq, s1part, QB,
                                          fc2_w, fc3_w, w2f, w3f, s2sum, s2sq);
  k_fc2stats<<<B / 128, 512, 0, stream>>>((const float4*)wq, s1part, QB,
                                          fc1_w, fc1_b, bn1_g, bn1_b,
                                          w2f, fc2_b, s2sum, s2sq, a1g, invB);
  k_final<<<B / 128, 512, 0, stream>>>(a1g, w2f, fc2_b, bn2_g, bn2_b,
                                       s2sum, s2sq, w3f, fc3_b, out, invB);
}

// Round 6
// 145.996 us; speedup vs baseline: 1.1029x; 1.1029x over previous
//
#include <hip/hip_runtime.h>

typedef __attribute__((ext_vector_type(8))) _Float16 f16x8;
typedef __attribute__((ext_vector_type(16))) float f32x16;

#define MFMA32(a, b, c) __builtin_amdgcn_mfma_f32_32x32x16_f16((a), (b), (c), 0, 0, 0)

// ---------------- helpers ----------------
__device__ __forceinline__ float tanh_fast(float x) {
  return 1.0f - 2.0f / (__expf(2.0f * x) + 1.0f);
}

// ---------------- K1: quantum sim -> q + per-block stat partials ----------------
// Tail blocks (48) convert weights to fp16 (8 elems/thread, 16B stores) and zero
// the s2 stat buffers (consumed only by K2, ordered by the dispatch boundary).
// The depth-2 RZ pass is omitted: it is a pure phase rotation immediately before
// |psi|^2 and cannot change any probability.
__global__ __launch_bounds__(256) void k_quantum(
    const float4* __restrict__ x, const float* __restrict__ qp,
    float4* __restrict__ qout, float* __restrict__ s1part, int QB,
    const float* __restrict__ w2, const float* __restrict__ w3,
    _Float16* __restrict__ w2f, _Float16* __restrict__ w3f,
    float* __restrict__ s2sum, float* __restrict__ s2sq)
{
  int tid = threadIdx.x;

  if (blockIdx.x >= QB) {   // weight-conversion tail blocks (48 of them)
    int tb = blockIdx.x - QB;
    int i = tb * 256 + tid;   // 0..12287
    if (i < 8192) {           // w3: 65536 elems, 8 per thread
      const float4* s = (const float4*)w3 + (size_t)i * 2;
      float4 lo = s[0], hi = s[1];
      f16x8 v;
      v[0] = (_Float16)lo.x; v[1] = (_Float16)lo.y; v[2] = (_Float16)lo.z; v[3] = (_Float16)lo.w;
      v[4] = (_Float16)hi.x; v[5] = (_Float16)hi.y; v[6] = (_Float16)hi.z; v[7] = (_Float16)hi.w;
      *(f16x8*)(w3f + (size_t)i * 8) = v;
    }
    if (i < 4096) {           // w2: 32768 elems, 8 per thread
      const float4* s = (const float4*)w2 + (size_t)i * 2;
      float4 lo = s[0], hi = s[1];
      f16x8 v;
      v[0] = (_Float16)lo.x; v[1] = (_Float16)lo.y; v[2] = (_Float16)lo.z; v[3] = (_Float16)lo.w;
      v[4] = (_Float16)hi.x; v[5] = (_Float16)hi.y; v[6] = (_Float16)hi.z; v[7] = (_Float16)hi.w;
      *(f16x8*)(w2f + (size_t)i * 8) = v;
    }
    if (tb == 0) { s2sum[tid] = 0.f; s2sq[tid] = 0.f; }
    return;
  }

  size_t r = (size_t)blockIdx.x * 256 + tid;
  float4 xr = x[r];
  float xv[4] = {xr.x, xr.y, xr.z, xr.w};

  float re[16], im[16];
#pragma unroll
  for (int i = 0; i < 16; i++) { re[i] = 0.f; im[i] = 0.f; }
  re[0] = 1.f;

#pragma unroll
  for (int d = 0; d < 3; d++) {
#pragma unroll
    for (int q = 0; q < 4; q++) {
      float th = 0.5f * (xv[q] + qp[d * 8 + q]);
      float s, c; __sincosf(th, &s, &c);
      int m = 8 >> q;
#pragma unroll
      for (int i = 0; i < 16; i++) if (!(i & m)) {
        int i1 = i | m;
        float r0 = re[i], i0 = im[i], r1 = re[i1], i1v = im[i1];
        re[i]  = c * r0 - s * r1;  im[i]  = c * i0 - s * i1v;
        re[i1] = s * r0 + c * r1;  im[i1] = s * i0 + c * i1v;
      }
    }
#pragma unroll
    for (int q = 0; q < 4; q++) {
      int mc = 8 >> q, mt = 8 >> ((q + 1) & 3);
#pragma unroll
      for (int i = 0; i < 16; i++) if ((i & mc) && !(i & mt)) {
        int i1 = i | mt;
        float tr = re[i]; re[i] = re[i1]; re[i1] = tr;
        float ti = im[i]; im[i] = im[i1]; im[i1] = ti;
      }
    }
    if (d != 2) {   // final-depth RZ is |.|^2-invariant: skip it
#pragma unroll
      for (int q = 0; q < 4; q++) {
        float th = 0.5f * qp[d * 8 + 4 + q];
        float s, c; __sincosf(th, &s, &c);
        int m = 8 >> q;
#pragma unroll
        for (int i = 0; i < 16; i++) {
          float pi = (i & m) ? s : -s;
          float r0 = re[i], i0 = im[i];
          re[i] = r0 * c - i0 * pi;
          im[i] = r0 * pi + i0 * c;
        }
      }
    }
  }

  float p[16];
#pragma unroll
  for (int i = 0; i < 16; i++) p[i] = re[i] * re[i] + im[i] * im[i];
  float z[4];
#pragma unroll
  for (int q = 0; q < 4; q++) {
    int m = 8 >> q; float acc = 0.f;
#pragma unroll
    for (int i = 0; i < 16; i++) acc += (i & m) ? -p[i] : p[i];
    z[q] = acc;
  }
  qout[r] = make_float4(z[0], z[1], z[2], z[3]);

  float st[14];
  st[0] = z[0]; st[1] = z[1]; st[2] = z[2]; st[3] = z[3];
  int p5 = 4;
#pragma unroll
  for (int a = 0; a < 4; a++)
#pragma unroll
    for (int b = a; b < 4; b++) st[p5++] = z[a] * z[b];

  __shared__ float part[4][14];
  int lane = tid & 63, wv = tid >> 6;
#pragma unroll
  for (int s = 0; s < 14; s++) {
    float v = st[s];
#pragma unroll
    for (int o = 32; o; o >>= 1) v += __shfl_down(v, o, 64);
    if (lane == 0) part[wv][s] = v;
  }
  __syncthreads();
  if (tid < 14)
    s1part[blockIdx.x * 14 + tid] =
        part[0][tid] + part[1][tid] + part[2][tid] + part[3][tid];
}

// ---------------- K2: reduce stats + fold BN1 (per block) -> fc2 MFMA -> BN2 stats ----------------
// 128 rows/block, 512 threads (8 waves x 32-col strips) for latency hiding.
__global__ __launch_bounds__(512, 4) void k_fc2stats(
    const float4* __restrict__ q, const float* __restrict__ s1part, int QB,
    const float* __restrict__ w1p, const float* __restrict__ b1p,
    const float* __restrict__ g1p, const float* __restrict__ bb1p,
    const _Float16* __restrict__ w2f, const float* __restrict__ b2,
    float* __restrict__ s2sum, float* __restrict__ s2sq, float invB)
{
  __shared__ __align__(16) float4 qs[128];                 // 2 KB
  __shared__ __align__(16) _Float16 a1[128 * 136];         // 34.8 KB
  __shared__ float r1[14][32];
  __shared__ float s1v[14];
  __shared__ __align__(16) float4 w1eS[128];
  __shared__ float b1eS[128];

  int t = threadIdx.x;
  int lane = t & 63, w = t >> 6, m32 = lane & 31, hh = lane >> 5;
  size_t rowBase = (size_t)blockIdx.x * 128;

  if (t < 128) qs[t] = q[rowBase + t];
  if (t < 448) {                       // reduce partials, 32-way per stat
    int s = t >> 5, k = t & 31;
    float acc = 0.f;
    for (int j = k; j < QB; j += 32) acc += s1part[j * 14 + s];
    r1[s][k] = acc;
  }
  __syncthreads();
  if (t < 14) {
    float v = 0.f;
#pragma unroll
    for (int k = 0; k < 32; k++) v += r1[t][k];
    s1v[t] = v * invB;
  }
  __syncthreads();

  // fold BN1 into effective fc1 weights (per block, in LDS)
  if (t < 128) {
    int j = t;
    float S0 = s1v[0], S1 = s1v[1], S2 = s1v[2], S3 = s1v[3];
    float M00 = s1v[4], M01 = s1v[5], M02 = s1v[6], M03 = s1v[7];
    float M11 = s1v[8], M12 = s1v[9], M13 = s1v[10];
    float M22 = s1v[11], M23 = s1v[12], M33 = s1v[13];
    float w0 = w1p[j * 4 + 0], wv1 = w1p[j * 4 + 1], wv2 = w1p[j * 4 + 2], wv3 = w1p[j * 4 + 3];
    float b = b1p[j];
    float wq = w0 * S0 + wv1 * S1 + wv2 * S2 + wv3 * S3;
    float mm = wq + b;
    float quad = w0 * w0 * M00 + wv1 * wv1 * M11 + wv2 * wv2 * M22 + wv3 * wv3 * M33
               + 2.f * (w0 * wv1 * M01 + w0 * wv2 * M02 + w0 * wv3 * M03
                      + wv1 * wv2 * M12 + wv1 * wv3 * M13 + wv2 * wv3 * M23);
    float e2 = quad + 2.f * b * wq + b * b;
    float var = e2 - mm * mm;
    float sv = g1p[j] * rsqrtf(var + 1e-5f);
    w1eS[j] = make_float4(sv * w0, sv * wv1, sv * wv2, sv * wv3);
    b1eS[j] = sv * b + bb1p[j] - sv * mm;
  }
  __syncthreads();

  // stage a1 = relu(W1e q + b1e) as fp16 (128 rows x 128 cols, 32 rows/thread)
  {
    int j = t & 127;
    float4 w1v = w1eS[j];
    float b1v = b1eS[j];
    int rb = (t >> 7) * 32;
#pragma unroll 8
    for (int i = 0; i < 32; i++) {
      float4 qv = qs[rb + i];
      float v = fmaf(w1v.x, qv.x, fmaf(w1v.y, qv.y, fmaf(w1v.z, qv.z, fmaf(w1v.w, qv.w, b1v))));
      a1[(rb + i) * 136 + j] = (_Float16)fmaxf(v, 0.f);
    }
  }
  __syncthreads();

  // fc2: wave w owns cols [w*32, w*32+32)
  f32x16 acc[4];
#pragma unroll
  for (int mt = 0; mt < 4; mt++)
#pragma unroll
    for (int r = 0; r < 16; r++) acc[mt][r] = 0.f;

  int col = w * 32 + m32;
#pragma unroll
  for (int ks = 0; ks < 8; ks++) {               // K = 128, step 16
    int kb = ks * 16 + hh * 8;
    f16x8 bfr = *(const f16x8*)(w2f + (size_t)col * 128 + kb);
#pragma unroll
    for (int mt = 0; mt < 4; mt++) {
      f16x8 afr = *(const f16x8*)&a1[(mt * 32 + m32) * 136 + kb];
      acc[mt] = MFMA32(afr, bfr, acc[mt]);
    }
  }

  // per-column sum & sumsq of h2 = acc + b2 over the block's 128 rows
  {
    float b2v = b2[col];
    float s = 0.f, ss = 0.f;
#pragma unroll
    for (int mt = 0; mt < 4; mt++)
#pragma unroll
      for (int r = 0; r < 16; r++) {
        float hv = acc[mt][r] + b2v;
        s += hv; ss += hv * hv;
      }
    s += __shfl_down(s, 32, 64);
    ss += __shfl_down(ss, 32, 64);
    if (lane < 32) {
      atomicAdd(&s2sum[col], s);
      atomicAdd(&s2sq[col], ss);
    }
  }
}

// ---------------- K3: reduce+fold (per block) -> fc2 -> BN2+ReLU -> fc3 -> tanh ----------------
// 128 rows/block, 512 threads (8 waves x 32-col strips), ~76 KB LDS -> 2 blocks/CU.
__global__ __launch_bounds__(512, 4) void k_final(
    const float4* __restrict__ q, const float* __restrict__ s1part, int QB,
    const float* __restrict__ w1p, const float* __restrict__ b1p,
    const float* __restrict__ g1p, const float* __restrict__ bb1p,
    const _Float16* __restrict__ w2f, const float* __restrict__ b2,
    const float* __restrict__ g2p, const float* __restrict__ bb2p,
    const float* __restrict__ s2sum, const float* __restrict__ s2sq,
    const _Float16* __restrict__ w3f, const float* __restrict__ b3,
    float* __restrict__ out, float invB)
{
  __shared__ __align__(16) float4 qs[128];                 // 2 KB
  __shared__ __align__(16) _Float16 un[128 * 264];         // 66 KB union a1/a2
  __shared__ float r1[14][32];
  __shared__ float s1v[14];
  __shared__ __align__(16) float4 w1eS[128];
  __shared__ float b1eS[128];
  __shared__ float sc2s[256];
  __shared__ float t2s[256];

  int t = threadIdx.x;
  int lane = t & 63, w = t >> 6, m32 = lane & 31, hh = lane >> 5;
  size_t rowBase = (size_t)blockIdx.x * 128;

  if (t < 128) qs[t] = q[rowBase + t];
  if (t < 448) {
    int s = t >> 5, k = t & 31;
    float acc = 0.f;
    for (int j = k; j < QB; j += 32) acc += s1part[j * 14 + s];
    r1[s][k] = acc;
  }
  // BN2 affine coefficients (first 256 threads; b2 folded in)
  if (t < 256) {
    float mcol = s2sum[t] * invB;
    float vcol = s2sq[t] * invB - mcol * mcol;
    float sv = g2p[t] * rsqrtf(vcol + 1e-5f);
    sc2s[t] = sv;
    t2s[t] = bb2p[t] - mcol * sv + b2[t] * sv;   // a2 = relu(sv*acc_nobias + t2)
  }
  __syncthreads();
  if (t < 14) {
    float v = 0.f;
#pragma unroll
    for (int k = 0; k < 32; k++) v += r1[t][k];
    s1v[t] = v * invB;
  }
  __syncthreads();

  if (t < 128) {
    int j = t;
    float S0 = s1v[0], S1 = s1v[1], S2 = s1v[2], S3 = s1v[3];
    float M00 = s1v[4], M01 = s1v[5], M02 = s1v[6], M03 = s1v[7];
    float M11 = s1v[8], M12 = s1v[9], M13 = s1v[10];
    float M22 = s1v[11], M23 = s1v[12], M33 = s1v[13];
    float w0 = w1p[j * 4 + 0], wv1 = w1p[j * 4 + 1], wv2 = w1p[j * 4 + 2], wv3 = w1p[j * 4 + 3];
    float b = b1p[j];
    float wq = w0 * S0 + wv1 * S1 + wv2 * S2 + wv3 * S3;
    float mm = wq + b;
    float quad = w0 * w0 * M00 + wv1 * wv1 * M11 + wv2 * wv2 * M22 + wv3 * wv3 * M33
               + 2.f * (w0 * wv1 * M01 + w0 * wv2 * M02 + w0 * wv3 * M03
                      + wv1 * wv2 * M12 + wv1 * wv3 * M13 + wv2 * wv3 * M23);
    float e2 = quad + 2.f * b * wq + b * b;
    float var = e2 - mm * mm;
    float sv = g1p[j] * rsqrtf(var + 1e-5f);
    w1eS[j] = make_float4(sv * w0, sv * wv1, sv * wv2, sv * wv3);
    b1eS[j] = sv * b + bb1p[j] - sv * mm;
  }
  __syncthreads();

  // ---- stage a1 (128 rows x 128 cols, 32 rows/thread) ----
  {
    int j = t & 127;
    float4 w1v = w1eS[j];
    float b1v = b1eS[j];
    int rb = (t >> 7) * 32;
#pragma unroll 8
    for (int i = 0; i < 32; i++) {
      float4 qv = qs[rb + i];
      float v = fmaf(w1v.x, qv.x, fmaf(w1v.y, qv.y, fmaf(w1v.z, qv.z, fmaf(w1v.w, qv.w, b1v))));
      un[(rb + i) * 136 + j] = (_Float16)fmaxf(v, 0.f);
    }
  }
  __syncthreads();

  // ---- fc2: wave w owns cols [w*32, w*32+32) ----
  int col = w * 32 + m32;
  f32x16 acc[4];
#pragma unroll
  for (int mt = 0; mt < 4; mt++)
#pragma unroll
    for (int r = 0; r < 16; r++) acc[mt][r] = 0.f;

#pragma unroll
  for (int ks = 0; ks < 8; ks++) {
    int kb = ks * 16 + hh * 8;
    f16x8 bfr = *(const f16x8*)(w2f + (size_t)col * 128 + kb);
#pragma unroll
    for (int mt = 0; mt < 4; mt++) {
      f16x8 afr = *(const f16x8*)&un[(mt * 32 + m32) * 136 + kb];
      acc[mt] = MFMA32(afr, bfr, acc[mt]);
    }
  }
  __syncthreads();   // all a1 reads done; union becomes a2

  // ---- BN2 + ReLU -> a2 (fp16) ----
  {
    float sv = sc2s[col], tv = t2s[col];
#pragma unroll
    for (int mt = 0; mt < 4; mt++)
#pragma unroll
      for (int r = 0; r < 16; r++) {
        int row = mt * 32 + (r & 3) + 8 * (r >> 2) + 4 * hh;
        un[row * 264 + col] = (_Float16)fmaxf(fmaf(acc[mt][r], sv, tv), 0.f);
      }
  }
  __syncthreads();

  // ---- fc3 (K = 256) ----
  f32x16 acc3[4];
#pragma unroll
  for (int mt = 0; mt < 4; mt++)
#pragma unroll
    for (int r = 0; r < 16; r++) acc3[mt][r] = 0.f;

#pragma unroll
  for (int ks = 0; ks < 16; ks++) {
    int kb = ks * 16 + hh * 8;
    f16x8 bfr = *(const f16x8*)(w3f + (size_t)col * 256 + kb);
#pragma unroll
    for (int mt = 0; mt < 4; mt++) {
      f16x8 afr = *(const f16x8*)&un[(mt * 32 + m32) * 264 + kb];
      acc3[mt] = MFMA32(afr, bfr, acc3[mt]);
    }
  }

  // ---- tanh epilogue ----
  {
    float b3v = b3[col];
#pragma unroll
    for (int mt = 0; mt < 4; mt++)
#pragma unroll
      for (int r = 0; r < 16; r++) {
        int row = mt * 32 + (r & 3) + 8 * (r >> 2) + 4 * hh;
        out[(rowBase + row) * 256 + col] = tanh_fast(acc3[mt][r] + b3v);
      }
  }
}

// ---------------- host launcher ----------------
extern "C" void kernel_launch(void* const* d_in, const int* in_sizes, int n_in,
                              void* d_out, int out_size, void* d_ws, size_t ws_size,
                              hipStream_t stream) {
  const float* x     = (const float*)d_in[0];
  const float* qp    = (const float*)d_in[1];
  const float* fc1_w = (const float*)d_in[2];
  const float* fc1_b = (const float*)d_in[3];
  const float* bn1_g = (const float*)d_in[4];
  const float* bn1_b = (const float*)d_in[5];
  const float* fc2_w = (const float*)d_in[6];
  const float* fc2_b = (const float*)d_in[7];
  const float* bn2_g = (const float*)d_in[8];
  const float* bn2_b = (const float*)d_in[9];
  const float* fc3_w = (const float*)d_in[10];
  const float* fc3_b = (const float*)d_in[11];
  float* out = (float*)d_out;
  float* ws  = (float*)d_ws;

  int B = in_sizes[0] / 4;
  int QB = B / 256;
  float invB = 1.0f / (float)B;

  // ws layout: q[B*4] f32 | s1part[QB*14] | s2sum[256] | s2sq[256] |
  //            w2f[32768] f16 | w3f[65536] f16      (no memset needed)
  float* wq     = ws;
  float* s1part = ws + (size_t)4 * B;
  float* s2sum  = s1part + (size_t)QB * 14;
  float* s2sq   = s2sum + 256;
  _Float16* w2f = (_Float16*)(s2sq + 256);
  _Float16* w3f = w2f + 32768;

  k_quantum<<<QB + 48, 256, 0, stream>>>((const float4*)x, qp, (float4*)wq, s1part, QB,
                                         fc2_w, fc3_w, w2f, w3f, s2sum, s2sq);
  k_fc2stats<<<B / 128, 512, 0, stream>>>((const float4*)wq, s1part, QB,
                                          fc1_w, fc1_b, bn1_g, bn1_b,
                                          w2f, fc2_b, s2sum, s2sq, invB);
  k_final<<<B / 128, 512, 0, stream>>>((const float4*)wq, s1part, QB,
                                       fc1_w, fc1_b, bn1_g, bn1_b,
                                       w2f, fc2_b, bn2_g, bn2_b,
                                       s2sum, s2sq, w3f, fc3_b, out, invB);
}